// Round 6
// baseline (45807.990 us; speedup 1.0000x reference)
//
#include <hip/hip_runtime.h>
#include <cstdint>
#include <cstddef>

// ---------------------------------------------------------------------------
// Parareal neural-ODE (MSZero_13761075216509)
// f(x) = tanh(x@W1 + b1) @ W2 ; fp32 via bf16 hi/lo 3-term split MFMA.
// R6: sequential substep 4 -> 3 dispatches: GEMM1 z1 with fused tanh+split
//     epilogue (64 WGs, prefetch-pipelined) replaces z4 GEMM1 + reduce_tanh.
//     Vectorized phase identical to R5.
// ---------------------------------------------------------------------------

typedef __attribute__((ext_vector_type(4))) float f32x4;
typedef __attribute__((ext_vector_type(8))) short s16x8;
typedef __attribute__((ext_vector_type(4))) unsigned short u16x4;

#define DEV __device__ __forceinline__

DEV unsigned short f2bf(float x) {
  union { float f; uint32_t u; } v; v.f = x;
  uint32_t r = v.u + 0x7FFFu + ((v.u >> 16) & 1u);   // RNE
  return (unsigned short)(r >> 16);
}
DEV float bf2f(unsigned short h) {
  union { uint32_t u; float f; } v; v.u = ((uint32_t)h) << 16; return v.f;
}
DEV void split2(float x, unsigned short &h, unsigned short &l) {
  h = f2bf(x);
  l = f2bf(x - bf2f(h));
}
DEV float fast_tanh(float z) {
  return 1.f - 2.f / (__expf(2.f * z) + 1.f);
}
DEV void gload16(const unsigned short* g, unsigned short* l) {
  __builtin_amdgcn_global_load_lds(
      (const __attribute__((address_space(1))) void*)g,
      (__attribute__((address_space(3))) void*)l, 16, 0, 0);
}

// ---------------------------------------------------------------------------
// GEMM: C[M,N] = A[M,K]*B[K,N]; A hi/lo bf16 [M][K], B pre-transposed hi/lo
// bf16 [N][K]. 3-term split: Ah*Bh + Ah*Bl + Al*Bh, fp32 MFMA accumulate.
// LDS tile: [128 rows][8 slots x 16B] per operand, phys slot = src ^ (row&7)
// (conflict-free b128 reads); double-buffered, prefetch-issue-early.
// EPI=1: v=tanh(acc+bias[col]) -> Oh/Ol bf16
// EPI=2: fp32 partial at Part + blockIdx.z*M*N (split-K)
// EPI=3: rk-update: a=(add?ACC:X)+a1*sdt*acc -> ACC ; xt=X+a2*sdt*acc -> Oh/Ol
// EPI=4: axpy-update: v=Xin+(a1+a2*sdt)*acc -> Xout fp32 + Oh/Ol split
// ---------------------------------------------------------------------------
template<int EPI>
__global__ __launch_bounds__(256, 2) void gemm_k(
    const unsigned short* __restrict__ Ah, const unsigned short* __restrict__ Al,
    const unsigned short* __restrict__ Bh, const unsigned short* __restrict__ Bl,
    const float* __restrict__ bias,
    float* __restrict__ Part,
    unsigned short* __restrict__ Oh, unsigned short* __restrict__ Ol,
    const float* __restrict__ Xin,
    float* __restrict__ ACCb,
    float* __restrict__ Xout,
    const float* __restrict__ tspan,
    float a1, float a2, int accAdd,
    int M, int N, int K, int KS)
{
  __shared__ unsigned short sA[2][128 * 64];
  __shared__ unsigned short sB[2][128 * 64];
  const int tid = threadIdx.x;
  const int w = tid >> 6, l = tid & 63;
  const int m0 = blockIdx.y * 128, n0 = blockIdx.x * 128;
  const size_t kbeg = (size_t)blockIdx.z * (size_t)KS;
  const int wm = (w >> 1) * 64, wn = (w & 1) * 64;

  f32x4 acc[4][4];
#pragma unroll
  for (int a = 0; a < 4; ++a)
#pragma unroll
    for (int b = 0; b < 4; ++b) acc[a][b] = (f32x4){0.f, 0.f, 0.f, 0.f};

  // staging geometry: call j of wave w writes bytes [w*1024 + j*4096 + lane*16)
  // -> row j*32 + w*8 + (l>>3), phys slot l&7; phys slot holds src ^ (row&7)
  const int rsub = w * 8 + (l >> 3);
  const int ssrc = (l & 7) ^ (l >> 3);
  const int shalf = ssrc >> 2;
  const int schunk = ssrc & 3;
  const unsigned short* gA = (shalf ? Al : Ah) + (size_t)(m0 + rsub) * K + kbeg + schunk * 8;
  const unsigned short* gB = (shalf ? Bl : Bh) + (size_t)(n0 + rsub) * K + kbeg + schunk * 8;
  const size_t gstep = (size_t)32 * (size_t)K;
  const int db = w * 512;

  // fragment-read: A[R0+(l&15)][k=(l>>4)*8..]; phys slot = (h*4+(l>>4))^(l&7)
  const int arow = (l & 15);
  const int slotH = ((l >> 4)) ^ (l & 7);
  const int slotL = (4 + (l >> 4)) ^ (l & 7);

  const int nk = KS >> 5;

  auto STAGE = [&](int buf, int kt) {
    const size_t ko = (size_t)kt * 32;
    unsigned short* da = &sA[buf][db];
    unsigned short* dbp = &sB[buf][db];
#pragma unroll
    for (int j = 0; j < 4; ++j) {
      gload16(gA + ko + (size_t)j * gstep, da + j * 2048);
      gload16(gB + ko + (size_t)j * gstep, dbp + j * 2048);
    }
  };

  STAGE(0, 0);
  __syncthreads();
  int cur = 0;

  for (int kt = 0; kt < nk; ++kt) {
    if (kt + 1 < nk) STAGE(cur ^ 1, kt + 1);
    const unsigned short* pa = &sA[cur][0];
    const unsigned short* pb = &sB[cur][0];
    s16x8 afh[4], afl[4], bfh[4], bfl[4];
#pragma unroll
    for (int mi = 0; mi < 4; ++mi) {
      const int rb = (wm + mi * 16 + arow) * 64;
      afh[mi] = *(const s16x8*)&pa[rb + slotH * 8];
      afl[mi] = *(const s16x8*)&pa[rb + slotL * 8];
    }
#pragma unroll
    for (int ni = 0; ni < 4; ++ni) {
      const int rb = (wn + ni * 16 + arow) * 64;
      bfh[ni] = *(const s16x8*)&pb[rb + slotH * 8];
      bfl[ni] = *(const s16x8*)&pb[rb + slotL * 8];
    }
#pragma unroll
    for (int mi = 0; mi < 4; ++mi)
#pragma unroll
      for (int ni = 0; ni < 4; ++ni) {
        acc[mi][ni] = __builtin_amdgcn_mfma_f32_16x16x32_bf16(afh[mi], bfh[ni], acc[mi][ni], 0, 0, 0);
        acc[mi][ni] = __builtin_amdgcn_mfma_f32_16x16x32_bf16(afh[mi], bfl[ni], acc[mi][ni], 0, 0, 0);
        acc[mi][ni] = __builtin_amdgcn_mfma_f32_16x16x32_bf16(afl[mi], bfh[ni], acc[mi][ni], 0, 0, 0);
      }
    __syncthreads();
    cur ^= 1;
  }

  // epilogue: row = wm+mi*16+(l>>4)*4+j, col = wn+ni*16+(l&15)
  const int colb = n0 + wn + (l & 15);
  const int rowb = m0 + wm + (l >> 4) * 4;
  const float sdt = (EPI >= 3) ? (tspan[1] - tspan[0]) * (1.0f / 7.0f) : 0.f;

  if (EPI == 1) {
#pragma unroll
    for (int mi = 0; mi < 4; ++mi)
#pragma unroll
      for (int ni = 0; ni < 4; ++ni) {
        const int col = colb + ni * 16;
        const float bc = bias[col];
#pragma unroll
        for (int j = 0; j < 4; ++j) {
          const size_t idx = (size_t)(rowb + mi * 16 + j) * N + col;
          const float v = fast_tanh(acc[mi][ni][j] + bc);
          unsigned short hh, ll; split2(v, hh, ll);
          Oh[idx] = hh; Ol[idx] = ll;
        }
      }
  } else if (EPI == 2) {
    float* dst = Part + (size_t)blockIdx.z * (size_t)M * N;
#pragma unroll
    for (int mi = 0; mi < 4; ++mi)
#pragma unroll
      for (int ni = 0; ni < 4; ++ni) {
        const int col = colb + ni * 16;
#pragma unroll
        for (int j = 0; j < 4; ++j)
          dst[(size_t)(rowb + mi * 16 + j) * N + col] = acc[mi][ni][j];
      }
  } else if (EPI == 3) {
    const float c1 = a1 * sdt, c2 = a2 * sdt;
#pragma unroll
    for (int mi = 0; mi < 4; ++mi)
#pragma unroll
      for (int ni = 0; ni < 4; ++ni) {
        const int col = colb + ni * 16;
#pragma unroll
        for (int j = 0; j < 4; ++j) {
          const size_t idx = (size_t)(rowb + mi * 16 + j) * N + col;
          const float f = acc[mi][ni][j];
          const float x = Xin[idx];
          const float a = (accAdd ? ACCb[idx] : x) + c1 * f;
          ACCb[idx] = a;
          const float xt = x + c2 * f;
          unsigned short hh, ll; split2(xt, hh, ll);
          Oh[idx] = hh; Ol[idx] = ll;
        }
      }
  } else {  // EPI == 4
    const float coef = a1 + a2 * sdt;
#pragma unroll
    for (int mi = 0; mi < 4; ++mi)
#pragma unroll
      for (int ni = 0; ni < 4; ++ni) {
        const int col = colb + ni * 16;
#pragma unroll
        for (int j = 0; j < 4; ++j) {
          const size_t idx = (size_t)(rowb + mi * 16 + j) * N + col;
          const float v = Xin[idx] + coef * acc[mi][ni][j];
          Xout[idx] = v;
          unsigned short hh, ll; split2(v, hh, ll);
          Oh[idx] = hh; Ol[idx] = ll;
        }
      }
  }
}

// ---------------------------------------------------------------------------
// seq GEMM2 finish: F = sum_z Part[z]; E = X + sdt*F; [Eout=E];
// v = E [+ Dv]; X = v (+ hi/lo split); [Bout=v]
// ---------------------------------------------------------------------------
__global__ void reduce_axpy_k(const float* __restrict__ part, int S, int MN4,
    const float* __restrict__ tspan,
    float* __restrict__ Xf, unsigned short* __restrict__ Xh, unsigned short* __restrict__ Xl,
    const float* __restrict__ Dv, float* __restrict__ Bout, float* __restrict__ Eout)
{
  const int i = blockIdx.x * blockDim.x + threadIdx.x;
  if (i >= MN4) return;
  const float sdt = (tspan[1] - tspan[0]) * (1.0f / 7.0f);
  const size_t MN = (size_t)MN4 * 4;
  const size_t o = 4 * (size_t)i;
  f32x4 s = *(const f32x4*)(part + o);
  for (int z = 1; z < S; ++z) s += *(const f32x4*)(part + (size_t)z * MN + o);
  f32x4 e = *(const f32x4*)(Xf + o) + sdt * s;
  if (Eout) *(f32x4*)(Eout + o) = e;
  f32x4 v = e;
  if (Dv) v += *(const f32x4*)(Dv + o);
  *(f32x4*)(Xf + o) = v;
  u16x4 hh, ll;
#pragma unroll
  for (int j = 0; j < 4; ++j) { unsigned short h_, l_; split2(v[j], h_, l_); hh[j] = h_; ll[j] = l_; }
  *(u16x4*)(Xh + o) = hh;
  *(u16x4*)(Xl + o) = ll;
  if (Bout) *(f32x4*)(Bout + o) = v;
}

// ---------------------------------------------------------------------------
__global__ void axpy_split_k(
    float* __restrict__ dstF, unsigned short* __restrict__ dstH,
    unsigned short* __restrict__ dstL,
    const float* __restrict__ A, const float* __restrict__ Fv,
    float coef, int n4)
{
  for (int i = blockIdx.x * blockDim.x + threadIdx.x; i < n4;
       i += gridDim.x * blockDim.x) {
    const size_t o = 4 * (size_t)i;
    const f32x4 a = *(const f32x4*)(A + o);
    const f32x4 f = *(const f32x4*)(Fv + o);
    f32x4 v = a + coef * f;
    *(f32x4*)(dstF + o) = v;
    if (dstH) {
      u16x4 hh, ll;
#pragma unroll
      for (int j = 0; j < 4; ++j) { unsigned short h_, l_; split2(v[j], h_, l_); hh[j] = h_; ll[j] = l_; }
      *(u16x4*)(dstH + o) = hh;
      *(u16x4*)(dstL + o) = ll;
    }
  }
}

// ---------------------------------------------------------------------------
__global__ void transpose_split_k(const float* __restrict__ W,
                                  unsigned short* __restrict__ Th,
                                  unsigned short* __restrict__ Tl,
                                  int K, int N)
{
  __shared__ float t[32][33];
  const int tx = threadIdx.x & 31, ty = threadIdx.x >> 5;
  const int n0 = blockIdx.x * 32, k0 = blockIdx.y * 32;
#pragma unroll
  for (int r = 0; r < 4; ++r) {
    const int row = ty + r * 8;
    t[row][tx] = W[(size_t)(k0 + row) * N + n0 + tx];
  }
  __syncthreads();
#pragma unroll
  for (int r = 0; r < 4; ++r) {
    const int row = ty + r * 8;
    const float v = t[tx][row];
    unsigned short hh, ll; split2(v, hh, ll);
    const size_t idx = (size_t)(n0 + row) * K + k0 + tx;
    Th[idx] = hh; Tl[idx] = ll;
  }
}

// ---------------------------------------------------------------------------
extern "C" void kernel_launch(void* const* d_in, const int* in_sizes, int n_in,
                              void* d_out, int out_size, void* d_ws, size_t ws_size,
                              hipStream_t stream)
{
  const float* Bin   = (const float*)d_in[0];
  const float* tspan = (const float*)d_in[1];
  const float* W1    = (const float*)d_in[2];
  const float* b1    = (const float*)d_in[3];
  const float* W2    = (const float*)d_in[4];

  const int n = in_sizes[1];                 // 16
  const int h = in_sizes[3];                 // 4096
  const int d = in_sizes[2] / h;             // 1024
  const int batch = in_sizes[0] / (n * d);   // 256
  const int S = 7;                           // fine_steps-1
  const int MAXIT = 2;
  const size_t NB = (size_t)batch * d;

  float* Bw = (float*)d_out;

  uint8_t* wsb = (uint8_t*)d_ws;
  size_t off = 0;
  auto carve = [&](size_t bytes) -> void* {
    off = (off + 255) & ~(size_t)255;
    void* p = wsb + off; off += bytes; return p;
  };

  const size_t WH = (size_t)d * h;
  unsigned short* W1Th = (unsigned short*)carve(WH * 2);
  unsigned short* W1Tl = (unsigned short*)carve(WH * 2);
  unsigned short* W2Th = (unsigned short*)carve(WH * 2);
  unsigned short* W2Tl = (unsigned short*)carve(WH * 2);
  float* Dbuf = (float*)carve((size_t)(n - 1) * NB * 4);
  float* Eb   = (float*)carve((size_t)n * NB * 4);

  // seq split-K partials for GEMM2: z=16 x batch x d (16 MB)
  const int SPL2 = 16;
  float* Part = (float*)carve((size_t)SPL2 * batch * d * 4);

  const size_t per_node = (size_t)batch * ((size_t)d * 24 + (size_t)h * 4);
  int c;
  {
    size_t remb = ws_size > off + (1u << 20) ? ws_size - off - (1u << 20) : 0;
    c = (int)(remb / per_node);
    if (c < 1) c = 1;
    if (c > n - 1) c = n - 1;
  }
  const size_t CE = (size_t)c * NB;
  float*          Cst = (float*)carve(CE * 4);
  unsigned short* Csh = (unsigned short*)carve(CE * 2);
  unsigned short* Csl = (unsigned short*)carve(CE * 2);
  float*          Xf  = (float*)carve(CE * 4);
  unsigned short* Xh  = (unsigned short*)carve(CE * 2);
  unsigned short* Xl  = (unsigned short*)carve(CE * 2);
  unsigned short* XTh = (unsigned short*)carve(CE * 2);
  unsigned short* XTl = (unsigned short*)carve(CE * 2);
  float*          ACC = (float*)carve(CE * 4);
  unsigned short* Yh  = (unsigned short*)carve((size_t)c * batch * h * 2);
  unsigned short* Yl  = (unsigned short*)carve((size_t)c * batch * h * 2);

  auto ewg = [](size_t n4) -> int {
    size_t g = (n4 + 255) / 256;
    if (g > 2048) g = 2048; if (g < 1) g = 1;
    return (int)g;
  };
  auto axpy = [&](float* dF, unsigned short* dH, unsigned short* dL,
                  const float* A, const float* Fv, float coef, size_t ne) {
    const int n4 = (int)(ne / 4);
    axpy_split_k<<<ewg(n4), 256, 0, stream>>>(dF, dH, dL, A, Fv, coef, n4);
  };
  auto g1 = [&](const unsigned short* xh, const unsigned short* xl, int M) {
    gemm_k<1><<<dim3(h / 128, M / 128, 1), 256, 0, stream>>>(
        xh, xl, W1Th, W1Tl, b1, nullptr, Yh, Yl,
        nullptr, nullptr, nullptr, tspan, 0.f, 0.f, 0, M, h, d, d);
  };
  auto g2rk = [&](int M, float a1, float a2, int add) {
    gemm_k<3><<<dim3(d / 128, M / 128, 1), 256, 0, stream>>>(
        Yh, Yl, W2Th, W2Tl, nullptr, nullptr, XTh, XTl,
        Xf, ACC, nullptr, tspan, a1, a2, add, M, d, h, h);
  };
  auto g2ax = [&](int M, float* dF, unsigned short* dH, unsigned short* dL,
                  const float* Xin, float a1, float a2) {
    gemm_k<4><<<dim3(d / 128, M / 128, 1), 256, 0, stream>>>(
        Yh, Yl, W2Th, W2Tl, nullptr, nullptr, dH, dL,
        Xin, nullptr, dF, tspan, a1, a2, 0, M, d, h, h);
  };

  // ---- prep ---------------------------------------------------------------
  hipMemcpyAsync(Bw, Bin, (size_t)n * NB * 4, hipMemcpyDeviceToDevice, stream);
  transpose_split_k<<<dim3(h / 32, d / 32), 256, 0, stream>>>(W1, W1Th, W1Tl, d, h);
  transpose_split_k<<<dim3(d / 32, h / 32), 256, 0, stream>>>(W2, W2Th, W2Tl, h, d);

  const int MN4d = (int)(NB / 4);                    // batch*d/4

  // ---- Parareal outer loop ------------------------------------------------
  for (int i = 1; i <= MAXIT + 1; ++i) {
    const int rem = n - i;

    for (int base = 0; base < rem; base += c) {
      const int cc = (rem - base) < c ? (rem - base) : c;
      const int M = cc * batch;
      const size_t ne = (size_t)M * d;
      const int j0 = i - 1 + base;
      const float* src = Bw + (size_t)j0 * NB;

      if (i == 1) {
        axpy(Cst, Csh, Csl, src, src, 0.f, ne);
        for (int s = 0; s < S; ++s) {
          g1(Csh, Csl, M);
          g2ax(M, Cst, Csh, Csl, Cst, 0.f, 1.f);
        }
      }
      axpy(Xf, Xh, Xl, src, src, 0.f, ne);
      for (int s = 0; s < S; ++s) {
        g1(Xh, Xl, M);   g2rk(M, 1.f / 6.f, 0.5f, 0);   // k1
        g1(XTh, XTl, M); g2rk(M, 1.f / 3.f, 0.5f, 1);   // k2
        g1(XTh, XTl, M); g2rk(M, 1.f / 3.f, 1.0f, 1);   // k3
        g1(XTh, XTl, M); g2ax(M, Xf, Xh, Xl, ACC, 0.f, 1.f / 6.f);  // k4
      }
      const float* Cref = (i == 1) ? Cst : (Eb + (size_t)j0 * NB);
      axpy(Dbuf + (size_t)base * NB, nullptr, nullptr, Xf, Cref, -1.f, ne);
    }

    // ---- sequential Parareal correction: 3 dispatches per substep ---------
    const float* start = Bw + (size_t)(i - 1) * NB;
    axpy(Xf, Xh, Xl, start, start, 0.f, NB);
    for (int m = 0; m < rem; ++m) {
      for (int s = 0; s < S; ++s) {
        // GEMM1 z1 with fused tanh+split epilogue: 32x2 = 64 WGs, 32-deep K
        g1(Xh, Xl, batch);
        // GEMM2 partials: 8 x 2 x 16 = 256 WGs, 8 K-steps each
        gemm_k<2><<<dim3(d / 128, batch / 128, SPL2), 256, 0, stream>>>(
            Yh, Yl, W2Th, W2Tl, nullptr, Part, nullptr, nullptr,
            nullptr, nullptr, nullptr, tspan, 0.f, 0.f, 0, batch, d, h, h / SPL2);
        const bool last = (s == S - 1);
        reduce_axpy_k<<<(MN4d + 255) / 256, 256, 0, stream>>>(
            Part, SPL2, MN4d, tspan, Xf, Xh, Xl,
            last ? Dbuf + (size_t)m * NB : nullptr,
            last ? Bw + (size_t)(i + m) * NB : nullptr,
            last ? Eb + (size_t)(i - 1 + m) * NB : nullptr);
      }
    }
  }
}

// Round 7
// 41423.801 us; speedup vs baseline: 1.1058x; 1.1058x over previous
//
#include <hip/hip_runtime.h>
#include <cstdint>
#include <cstddef>

// ---------------------------------------------------------------------------
// Parareal neural-ODE (MSZero_13761075216509)
// f(x) = tanh(x@W1 + b1) @ W2 ; fp32 via bf16 hi/lo 3-term split MFMA.
// R7: R5 structure + vectorized GEMM2 z-split (SPL=4 -> 64*cc WGs, 32 K-steps)
//     with fused reduce+RK-update+split kernel. R6's z1 seq-g1 reverted.
//     Measured basis: R6 showed ~1 blk/CU deep-K GEMMs run ~1.2us/K-step.
// ---------------------------------------------------------------------------

typedef __attribute__((ext_vector_type(4))) float f32x4;
typedef __attribute__((ext_vector_type(8))) short s16x8;
typedef __attribute__((ext_vector_type(4))) unsigned short u16x4;

#define DEV __device__ __forceinline__

DEV unsigned short f2bf(float x) {
  union { float f; uint32_t u; } v; v.f = x;
  uint32_t r = v.u + 0x7FFFu + ((v.u >> 16) & 1u);   // RNE
  return (unsigned short)(r >> 16);
}
DEV float bf2f(unsigned short h) {
  union { uint32_t u; float f; } v; v.u = ((uint32_t)h) << 16; return v.f;
}
DEV void split2(float x, unsigned short &h, unsigned short &l) {
  h = f2bf(x);
  l = f2bf(x - bf2f(h));
}
DEV float fast_tanh(float z) {
  return 1.f - 2.f / (__expf(2.f * z) + 1.f);
}
DEV void gload16(const unsigned short* g, unsigned short* l) {
  __builtin_amdgcn_global_load_lds(
      (const __attribute__((address_space(1))) void*)g,
      (__attribute__((address_space(3))) void*)l, 16, 0, 0);
}

// ---------------------------------------------------------------------------
// GEMM: C[M,N] = A[M,K]*B[K,N]; A hi/lo bf16 [M][K], B pre-transposed hi/lo
// bf16 [N][K]. 3-term split: Ah*Bh + Ah*Bl + Al*Bh, fp32 MFMA accumulate.
// LDS tile: [128 rows][8 slots x 16B] per operand, phys slot = src ^ (row&7)
// (conflict-free b128 reads); double-buffered, prefetch-issue-early.
// EPI=1: v=tanh(acc+bias[col]) -> Oh/Ol bf16
// EPI=2: fp32 partial at Part + blockIdx.z*M*N (split-K over z)
// ---------------------------------------------------------------------------
template<int EPI>
__global__ __launch_bounds__(256, 2) void gemm_k(
    const unsigned short* __restrict__ Ah, const unsigned short* __restrict__ Al,
    const unsigned short* __restrict__ Bh, const unsigned short* __restrict__ Bl,
    const float* __restrict__ bias,
    float* __restrict__ Part,
    unsigned short* __restrict__ Oh, unsigned short* __restrict__ Ol,
    int M, int N, int K, int KS)
{
  __shared__ unsigned short sA[2][128 * 64];
  __shared__ unsigned short sB[2][128 * 64];
  const int tid = threadIdx.x;
  const int w = tid >> 6, l = tid & 63;
  const int m0 = blockIdx.y * 128, n0 = blockIdx.x * 128;
  const size_t kbeg = (size_t)blockIdx.z * (size_t)KS;
  const int wm = (w >> 1) * 64, wn = (w & 1) * 64;

  f32x4 acc[4][4];
#pragma unroll
  for (int a = 0; a < 4; ++a)
#pragma unroll
    for (int b = 0; b < 4; ++b) acc[a][b] = (f32x4){0.f, 0.f, 0.f, 0.f};

  // staging: call j of wave w writes bytes [w*1024 + j*4096 + lane*16)
  // -> row j*32 + w*8 + (l>>3), phys slot l&7; phys slot holds src ^ (row&7)
  const int rsub = w * 8 + (l >> 3);
  const int ssrc = (l & 7) ^ (l >> 3);
  const int shalf = ssrc >> 2;
  const int schunk = ssrc & 3;
  const unsigned short* gA = (shalf ? Al : Ah) + (size_t)(m0 + rsub) * K + kbeg + schunk * 8;
  const unsigned short* gB = (shalf ? Bl : Bh) + (size_t)(n0 + rsub) * K + kbeg + schunk * 8;
  const size_t gstep = (size_t)32 * (size_t)K;
  const int db = w * 512;

  // fragment-read: A[R0+(l&15)][k=(l>>4)*8..]; phys slot = (h*4+(l>>4))^(l&7)
  const int arow = (l & 15);
  const int slotH = ((l >> 4)) ^ (l & 7);
  const int slotL = (4 + (l >> 4)) ^ (l & 7);

  const int nk = KS >> 5;

  auto STAGE = [&](int buf, int kt) {
    const size_t ko = (size_t)kt * 32;
    unsigned short* da = &sA[buf][db];
    unsigned short* dbp = &sB[buf][db];
#pragma unroll
    for (int j = 0; j < 4; ++j) {
      gload16(gA + ko + (size_t)j * gstep, da + j * 2048);
      gload16(gB + ko + (size_t)j * gstep, dbp + j * 2048);
    }
  };

  STAGE(0, 0);
  __syncthreads();
  int cur = 0;

  for (int kt = 0; kt < nk; ++kt) {
    if (kt + 1 < nk) STAGE(cur ^ 1, kt + 1);
    const unsigned short* pa = &sA[cur][0];
    const unsigned short* pb = &sB[cur][0];
    s16x8 afh[4], afl[4], bfh[4], bfl[4];
#pragma unroll
    for (int mi = 0; mi < 4; ++mi) {
      const int rb = (wm + mi * 16 + arow) * 64;
      afh[mi] = *(const s16x8*)&pa[rb + slotH * 8];
      afl[mi] = *(const s16x8*)&pa[rb + slotL * 8];
    }
#pragma unroll
    for (int ni = 0; ni < 4; ++ni) {
      const int rb = (wn + ni * 16 + arow) * 64;
      bfh[ni] = *(const s16x8*)&pb[rb + slotH * 8];
      bfl[ni] = *(const s16x8*)&pb[rb + slotL * 8];
    }
#pragma unroll
    for (int mi = 0; mi < 4; ++mi)
#pragma unroll
      for (int ni = 0; ni < 4; ++ni) {
        acc[mi][ni] = __builtin_amdgcn_mfma_f32_16x16x32_bf16(afh[mi], bfh[ni], acc[mi][ni], 0, 0, 0);
        acc[mi][ni] = __builtin_amdgcn_mfma_f32_16x16x32_bf16(afh[mi], bfl[ni], acc[mi][ni], 0, 0, 0);
        acc[mi][ni] = __builtin_amdgcn_mfma_f32_16x16x32_bf16(afl[mi], bfh[ni], acc[mi][ni], 0, 0, 0);
      }
    __syncthreads();
    cur ^= 1;
  }

  // epilogue: row = wm+mi*16+(l>>4)*4+j, col = wn+ni*16+(l&15)
  const int colb = n0 + wn + (l & 15);
  const int rowb = m0 + wm + (l >> 4) * 4;

  if (EPI == 1) {
#pragma unroll
    for (int mi = 0; mi < 4; ++mi)
#pragma unroll
      for (int ni = 0; ni < 4; ++ni) {
        const int col = colb + ni * 16;
        const float bc = bias[col];
#pragma unroll
        for (int j = 0; j < 4; ++j) {
          const size_t idx = (size_t)(rowb + mi * 16 + j) * N + col;
          const float v = fast_tanh(acc[mi][ni][j] + bc);
          unsigned short hh, ll; split2(v, hh, ll);
          Oh[idx] = hh; Ol[idx] = ll;
        }
      }
  } else {
    float* dst = Part + (size_t)blockIdx.z * (size_t)M * N;
#pragma unroll
    for (int mi = 0; mi < 4; ++mi)
#pragma unroll
      for (int ni = 0; ni < 4; ++ni) {
        const int col = colb + ni * 16;
#pragma unroll
        for (int j = 0; j < 4; ++j)
          dst[(size_t)(rowb + mi * 16 + j) * N + col] = acc[mi][ni][j];
      }
  }
}

// ---------------------------------------------------------------------------
// vect GEMM2 finish: F = sum_z Part[z]; RK/Euler update + bf16 hi/lo split.
// mode 0: X = X + sdt*F            -> X, hOut/lOut = split(X)
// mode 1: ACC = X + (sdt/6)F ; v = X + (sdt/2)F -> hOut/lOut = split(v)
// mode 2: ACC += (sdt/3)F    ; v = X + (sdt/2)F -> split(v)
// mode 3: ACC += (sdt/3)F    ; v = X + sdt*F    -> split(v)
// mode 4: X = ACC + (sdt/6)F       -> X, split(X)
// ---------------------------------------------------------------------------
__global__ void reduce_upd_k(const float* __restrict__ Part, int SPL, int MN4,
    const float* __restrict__ tspan, int mode,
    float* __restrict__ X, float* __restrict__ ACC,
    unsigned short* __restrict__ hOut, unsigned short* __restrict__ lOut)
{
  const int i = blockIdx.x * blockDim.x + threadIdx.x;
  if (i >= MN4) return;
  const float sdt = (tspan[1] - tspan[0]) * (1.0f / 7.0f);
  const size_t MN = (size_t)MN4 * 4;
  const size_t o = 4 * (size_t)i;
  f32x4 F = *(const f32x4*)(Part + o);
  for (int z = 1; z < SPL; ++z) F += *(const f32x4*)(Part + (size_t)z * MN + o);

  f32x4 v;
  if (mode == 0) {
    v = *(const f32x4*)(X + o) + sdt * F;
    *(f32x4*)(X + o) = v;
  } else if (mode == 1) {
    const f32x4 x = *(const f32x4*)(X + o);
    *(f32x4*)(ACC + o) = x + (sdt * (1.f / 6.f)) * F;
    v = x + (sdt * 0.5f) * F;
  } else if (mode == 2) {
    const f32x4 x = *(const f32x4*)(X + o);
    *(f32x4*)(ACC + o) = *(const f32x4*)(ACC + o) + (sdt * (1.f / 3.f)) * F;
    v = x + (sdt * 0.5f) * F;
  } else if (mode == 3) {
    const f32x4 x = *(const f32x4*)(X + o);
    *(f32x4*)(ACC + o) = *(const f32x4*)(ACC + o) + (sdt * (1.f / 3.f)) * F;
    v = x + sdt * F;
  } else {
    v = *(const f32x4*)(ACC + o) + (sdt * (1.f / 6.f)) * F;
    *(f32x4*)(X + o) = v;
  }
  u16x4 hh, ll;
#pragma unroll
  for (int j = 0; j < 4; ++j) { unsigned short h_, l_; split2(v[j], h_, l_); hh[j] = h_; ll[j] = l_; }
  *(u16x4*)(hOut + o) = hh;
  *(u16x4*)(lOut + o) = ll;
}

// ---------------------------------------------------------------------------
// Y = tanh(sum_z Part[z] + bias[col]) -> Yh/Yl (seq GEMM1 finish)
// ---------------------------------------------------------------------------
__global__ void reduce_tanh_k(const float* __restrict__ Part, int SPL, int MN4,
    const float* __restrict__ bias, int N,
    unsigned short* __restrict__ Yh, unsigned short* __restrict__ Yl)
{
  const int i = blockIdx.x * blockDim.x + threadIdx.x;
  if (i >= MN4) return;
  const size_t MN = (size_t)MN4 * 4;
  const size_t o = 4 * (size_t)i;
  f32x4 s = *(const f32x4*)(Part + o);
  for (int z = 1; z < SPL; ++z) s += *(const f32x4*)(Part + (size_t)z * MN + o);
  const int col = (int)(o % (size_t)N);
  const f32x4 b = *(const f32x4*)(bias + col);
  u16x4 hh, ll;
#pragma unroll
  for (int j = 0; j < 4; ++j) {
    const float v = fast_tanh(s[j] + b[j]);
    unsigned short h_, l_; split2(v, h_, l_);
    hh[j] = h_; ll[j] = l_;
  }
  *(u16x4*)(Yh + o) = hh;
  *(u16x4*)(Yl + o) = ll;
}

// ---------------------------------------------------------------------------
// seq GEMM2 finish: F = sum_z Part[z]; E = X + sdt*F; [Eout=E];
// v = E [+ Dv]; X = v (+ hi/lo split); [Bout=v]
// ---------------------------------------------------------------------------
__global__ void reduce_axpy_k(const float* __restrict__ part, int S, int MN4,
    const float* __restrict__ tspan,
    float* __restrict__ Xf, unsigned short* __restrict__ Xh, unsigned short* __restrict__ Xl,
    const float* __restrict__ Dv, float* __restrict__ Bout, float* __restrict__ Eout)
{
  const int i = blockIdx.x * blockDim.x + threadIdx.x;
  if (i >= MN4) return;
  const float sdt = (tspan[1] - tspan[0]) * (1.0f / 7.0f);
  const size_t MN = (size_t)MN4 * 4;
  const size_t o = 4 * (size_t)i;
  f32x4 s = *(const f32x4*)(part + o);
  for (int z = 1; z < S; ++z) s += *(const f32x4*)(part + (size_t)z * MN + o);
  f32x4 e = *(const f32x4*)(Xf + o) + sdt * s;
  if (Eout) *(f32x4*)(Eout + o) = e;
  f32x4 v = e;
  if (Dv) v += *(const f32x4*)(Dv + o);
  *(f32x4*)(Xf + o) = v;
  u16x4 hh, ll;
#pragma unroll
  for (int j = 0; j < 4; ++j) { unsigned short h_, l_; split2(v[j], h_, l_); hh[j] = h_; ll[j] = l_; }
  *(u16x4*)(Xh + o) = hh;
  *(u16x4*)(Xl + o) = ll;
  if (Bout) *(f32x4*)(Bout + o) = v;
}

// ---------------------------------------------------------------------------
__global__ void axpy_split_k(
    float* __restrict__ dstF, unsigned short* __restrict__ dstH,
    unsigned short* __restrict__ dstL,
    const float* __restrict__ A, const float* __restrict__ Fv,
    float coef, int n4)
{
  for (int i = blockIdx.x * blockDim.x + threadIdx.x; i < n4;
       i += gridDim.x * blockDim.x) {
    const size_t o = 4 * (size_t)i;
    const f32x4 a = *(const f32x4*)(A + o);
    const f32x4 f = *(const f32x4*)(Fv + o);
    f32x4 v = a + coef * f;
    *(f32x4*)(dstF + o) = v;
    if (dstH) {
      u16x4 hh, ll;
#pragma unroll
      for (int j = 0; j < 4; ++j) { unsigned short h_, l_; split2(v[j], h_, l_); hh[j] = h_; ll[j] = l_; }
      *(u16x4*)(dstH + o) = hh;
      *(u16x4*)(dstL + o) = ll;
    }
  }
}

// ---------------------------------------------------------------------------
__global__ void transpose_split_k(const float* __restrict__ W,
                                  unsigned short* __restrict__ Th,
                                  unsigned short* __restrict__ Tl,
                                  int K, int N)
{
  __shared__ float t[32][33];
  const int tx = threadIdx.x & 31, ty = threadIdx.x >> 5;
  const int n0 = blockIdx.x * 32, k0 = blockIdx.y * 32;
#pragma unroll
  for (int r = 0; r < 4; ++r) {
    const int row = ty + r * 8;
    t[row][tx] = W[(size_t)(k0 + row) * N + n0 + tx];
  }
  __syncthreads();
#pragma unroll
  for (int r = 0; r < 4; ++r) {
    const int row = ty + r * 8;
    const float v = t[tx][row];
    unsigned short hh, ll; split2(v, hh, ll);
    const size_t idx = (size_t)(n0 + row) * K + k0 + tx;
    Th[idx] = hh; Tl[idx] = ll;
  }
}

// ---------------------------------------------------------------------------
extern "C" void kernel_launch(void* const* d_in, const int* in_sizes, int n_in,
                              void* d_out, int out_size, void* d_ws, size_t ws_size,
                              hipStream_t stream)
{
  const float* Bin   = (const float*)d_in[0];
  const float* tspan = (const float*)d_in[1];
  const float* W1    = (const float*)d_in[2];
  const float* b1    = (const float*)d_in[3];
  const float* W2    = (const float*)d_in[4];

  const int n = in_sizes[1];                 // 16
  const int h = in_sizes[3];                 // 4096
  const int d = in_sizes[2] / h;             // 1024
  const int batch = in_sizes[0] / (n * d);   // 256
  const int S = 7;                           // fine_steps-1
  const int MAXIT = 2;
  const size_t NB = (size_t)batch * d;

  float* Bw = (float*)d_out;

  uint8_t* wsb = (uint8_t*)d_ws;
  size_t off = 0;
  auto carve = [&](size_t bytes) -> void* {
    off = (off + 255) & ~(size_t)255;
    void* p = wsb + off; off += bytes; return p;
  };

  const size_t WH = (size_t)d * h;
  unsigned short* W1Th = (unsigned short*)carve(WH * 2);
  unsigned short* W1Tl = (unsigned short*)carve(WH * 2);
  unsigned short* W2Th = (unsigned short*)carve(WH * 2);
  unsigned short* W2Tl = (unsigned short*)carve(WH * 2);
  float* Dbuf = (float*)carve((size_t)(n - 1) * NB * 4);
  float* Eb   = (float*)carve((size_t)n * NB * 4);

  const int SPL1 = 4;    // seq GEMM1 split
  const int SPL2 = 16;   // seq GEMM2 split
  const int SPLV = 4;    // vect GEMM2 split

  // chunk width (per node: 24B/elem state+splits + Y 4MB + Part SPLV*4MB)
  const size_t per_node = NB * 24 + (size_t)batch * h * 4 + NB * 4 * SPLV;
  int c;
  {
    const size_t resv = (size_t)18 << 20;   // seq Part (16.8MB) + slack
    size_t remb = ws_size > off + resv ? ws_size - off - resv : 0;
    c = (int)(remb / per_node);
    if (c < 1) c = 1;
    if (c > n - 1) c = n - 1;
  }
  const size_t CE = (size_t)c * NB;
  const size_t partElems = ((size_t)SPLV * c > 16 ? (size_t)SPLV * c : 16) * NB;
  float*          Part = (float*)carve(partElems * 4);
  float*          Cst = (float*)carve(CE * 4);
  unsigned short* Csh = (unsigned short*)carve(CE * 2);
  unsigned short* Csl = (unsigned short*)carve(CE * 2);
  float*          Xf  = (float*)carve(CE * 4);
  unsigned short* Xh  = (unsigned short*)carve(CE * 2);
  unsigned short* Xl  = (unsigned short*)carve(CE * 2);
  unsigned short* XTh = (unsigned short*)carve(CE * 2);
  unsigned short* XTl = (unsigned short*)carve(CE * 2);
  float*          ACC = (float*)carve(CE * 4);
  unsigned short* Yh  = (unsigned short*)carve((size_t)c * batch * h * 2);
  unsigned short* Yl  = (unsigned short*)carve((size_t)c * batch * h * 2);

  auto ewg = [](size_t n4) -> int {
    size_t g = (n4 + 255) / 256;
    if (g > 2048) g = 2048; if (g < 1) g = 1;
    return (int)g;
  };
  auto axpy = [&](float* dF, unsigned short* dH, unsigned short* dL,
                  const float* A, const float* Fv, float coef, size_t ne) {
    const int n4 = (int)(ne / 4);
    axpy_split_k<<<ewg(n4), 256, 0, stream>>>(dF, dH, dL, A, Fv, coef, n4);
  };
  // g1: fused tanh+split epilogue (z=1); WGs = 32 * (M/128)
  auto g1 = [&](const unsigned short* xh, const unsigned short* xl, int M) {
    gemm_k<1><<<dim3(h / 128, M / 128, 1), 256, 0, stream>>>(
        xh, xl, W1Th, W1Tl, b1, nullptr, Yh, Yl, M, h, d, d);
  };
  // vect g2: z-split partials; WGs = 8 * (M/128) * SPLV, 32 K-steps
  auto g2z = [&](int M) {
    gemm_k<2><<<dim3(d / 128, M / 128, SPLV), 256, 0, stream>>>(
        Yh, Yl, W2Th, W2Tl, nullptr, Part, nullptr, nullptr, M, d, h, h / SPLV);
  };
  auto red = [&](int M, int mode, float* X, unsigned short* hO, unsigned short* lO) {
    const int mn4 = (int)((size_t)M * d / 4);
    reduce_upd_k<<<(mn4 + 255) / 256, 256, 0, stream>>>(
        Part, SPLV, mn4, tspan, mode, X, ACC, hO, lO);
  };

  // ---- prep ---------------------------------------------------------------
  hipMemcpyAsync(Bw, Bin, (size_t)n * NB * 4, hipMemcpyDeviceToDevice, stream);
  transpose_split_k<<<dim3(h / 32, d / 32), 256, 0, stream>>>(W1, W1Th, W1Tl, d, h);
  transpose_split_k<<<dim3(d / 32, h / 32), 256, 0, stream>>>(W2, W2Th, W2Tl, h, d);

  const int MN4d = (int)(NB / 4);                    // batch*d/4
  const int MN4h = (int)((size_t)batch * h / 4);     // batch*h/4

  // ---- Parareal outer loop ------------------------------------------------
  for (int i = 1; i <= MAXIT + 1; ++i) {
    const int rem = n - i;

    for (int base = 0; base < rem; base += c) {
      const int cc = (rem - base) < c ? (rem - base) : c;
      const int M = cc * batch;
      const size_t ne = (size_t)M * d;
      const int j0 = i - 1 + base;
      const float* src = Bw + (size_t)j0 * NB;

      if (i == 1) {
        // coarse Euler sweep (i>=2 reuses Eb from previous sequential phase)
        axpy(Cst, Csh, Csl, src, src, 0.f, ne);
        for (int s = 0; s < S; ++s) {
          g1(Csh, Csl, M); g2z(M);
          red(M, 0, Cst, Csh, Csl);
        }
      }
      // fine RK4 sweep
      axpy(Xf, Xh, Xl, src, src, 0.f, ne);
      for (int s = 0; s < S; ++s) {
        g1(Xh, Xl, M);   g2z(M); red(M, 1, Xf, XTh, XTl);   // k1
        g1(XTh, XTl, M); g2z(M); red(M, 2, Xf, XTh, XTl);   // k2
        g1(XTh, XTl, M); g2z(M); red(M, 3, Xf, XTh, XTl);   // k3
        g1(XTh, XTl, M); g2z(M); red(M, 4, Xf, Xh, Xl);     // k4
      }
      const float* Cref = (i == 1) ? Cst : (Eb + (size_t)j0 * NB);
      axpy(Dbuf + (size_t)base * NB, nullptr, nullptr, Xf, Cref, -1.f, ne);
    }

    // ---- sequential Parareal correction (R5 structure, proven) ------------
    const float* start = Bw + (size_t)(i - 1) * NB;
    axpy(Xf, Xh, Xl, start, start, 0.f, NB);
    for (int m = 0; m < rem; ++m) {
      for (int s = 0; s < S; ++s) {
        gemm_k<2><<<dim3(h / 128, batch / 128, SPL1), 256, 0, stream>>>(
            Xh, Xl, W1Th, W1Tl, nullptr, Part, nullptr, nullptr,
            batch, h, d, d / SPL1);
        reduce_tanh_k<<<(MN4h + 255) / 256, 256, 0, stream>>>(
            Part, SPL1, MN4h, b1, h, Yh, Yl);
        gemm_k<2><<<dim3(d / 128, batch / 128, SPL2), 256, 0, stream>>>(
            Yh, Yl, W2Th, W2Tl, nullptr, Part, nullptr, nullptr,
            batch, d, h, h / SPL2);
        const bool last = (s == S - 1);
        reduce_axpy_k<<<(MN4d + 255) / 256, 256, 0, stream>>>(
            Part, SPL2, MN4d, tspan, Xf, Xh, Xl,
            last ? Dbuf + (size_t)m * NB : nullptr,
            last ? Bw + (size_t)(i + m) * NB : nullptr,
            last ? Eb + (size_t)(i - 1 + m) * NB : nullptr);
      }
    }
  }
}

// Round 9
// 36838.788 us; speedup vs baseline: 1.2435x; 1.1245x over previous
//
#include <hip/hip_runtime.h>
#include <cstdint>
#include <cstddef>

// ---------------------------------------------------------------------------
// Parareal neural-ODE (MSZero_13761075216509)
// f(x) = tanh(x@W1 + b1) @ W2 ; fp32 via bf16 hi/lo 3-term split MFMA.
// R9: R5 (37.3ms best) + sequential substep redesigned to 3 dispatches with
//     64x64-tile GEMMs at full-chip width (256 WGs each): g1 z1 fused-tanh,
//     g2 z4 -> Part(4.2MB), reduce_axpy S=4. XT aliases Cs; Part shrunk.
//     (R8 cooperative path abandoned: cross-XCD L2 staleness on readers.)
// ---------------------------------------------------------------------------

typedef __attribute__((ext_vector_type(4))) float f32x4;
typedef __attribute__((ext_vector_type(8))) short s16x8;
typedef __attribute__((ext_vector_type(4))) unsigned short u16x4;

#define DEV __device__ __forceinline__

DEV unsigned short f2bf(float x) {
  union { float f; uint32_t u; } v; v.f = x;
  uint32_t r = v.u + 0x7FFFu + ((v.u >> 16) & 1u);   // RNE
  return (unsigned short)(r >> 16);
}
DEV float bf2f(unsigned short h) {
  union { uint32_t u; float f; } v; v.u = ((uint32_t)h) << 16; return v.f;
}
DEV void split2(float x, unsigned short &h, unsigned short &l) {
  h = f2bf(x);
  l = f2bf(x - bf2f(h));
}
DEV float fast_tanh(float z) {
  return 1.f - 2.f / (__expf(2.f * z) + 1.f);
}
DEV void gload16(const unsigned short* g, unsigned short* l) {
  __builtin_amdgcn_global_load_lds(
      (const __attribute__((address_space(1))) void*)g,
      (__attribute__((address_space(3))) void*)l, 16, 0, 0);
}

// ---------------------------------------------------------------------------
// 128x128 GEMM (R5, unchanged): C[M,N] = A[M,K]*B[K,N]; A hi/lo bf16 [M][K],
// B pre-transposed hi/lo bf16 [N][K]. Ah*Bh + Ah*Bl + Al*Bh, fp32 MFMA acc.
// LDS [128 rows][8 slots x 16B]/operand, phys slot = src ^ (row&7); dbuf,
// prefetch-issue-early.
// EPI=1: v=tanh(acc+bias[col]) -> Oh/Ol bf16
// EPI=3: rk-update: a=(add?ACC:X)+a1*sdt*acc -> ACC ; xt=X+a2*sdt*acc -> Oh/Ol
// EPI=4: axpy-update: v=Xin+(a1+a2*sdt)*acc -> Xout fp32 + Oh/Ol split
// ---------------------------------------------------------------------------
template<int EPI>
__global__ __launch_bounds__(256, 2) void gemm_k(
    const unsigned short* __restrict__ Ah, const unsigned short* __restrict__ Al,
    const unsigned short* __restrict__ Bh, const unsigned short* __restrict__ Bl,
    const float* __restrict__ bias,
    unsigned short* __restrict__ Oh, unsigned short* __restrict__ Ol,
    const float* __restrict__ Xin,
    float* __restrict__ ACCb,
    float* __restrict__ Xout,
    const float* __restrict__ tspan,
    float a1, float a2, int accAdd,
    int M, int N, int K, int KS)
{
  __shared__ unsigned short sA[2][128 * 64];
  __shared__ unsigned short sB[2][128 * 64];
  const int tid = threadIdx.x;
  const int w = tid >> 6, l = tid & 63;
  const int m0 = blockIdx.y * 128, n0 = blockIdx.x * 128;
  const int wm = (w >> 1) * 64, wn = (w & 1) * 64;

  f32x4 acc[4][4];
#pragma unroll
  for (int a = 0; a < 4; ++a)
#pragma unroll
    for (int b = 0; b < 4; ++b) acc[a][b] = (f32x4){0.f, 0.f, 0.f, 0.f};

  const int rsub = w * 8 + (l >> 3);
  const int ssrc = (l & 7) ^ (l >> 3);
  const int shalf = ssrc >> 2;
  const int schunk = ssrc & 3;
  const unsigned short* gA = (shalf ? Al : Ah) + (size_t)(m0 + rsub) * K + schunk * 8;
  const unsigned short* gB = (shalf ? Bl : Bh) + (size_t)(n0 + rsub) * K + schunk * 8;
  const size_t gstep = (size_t)32 * (size_t)K;
  const int db = w * 512;

  const int arow = (l & 15);
  const int slotH = ((l >> 4)) ^ (l & 7);
  const int slotL = (4 + (l >> 4)) ^ (l & 7);

  const int nk = KS >> 5;

  auto STAGE = [&](int buf, int kt) {
    const size_t ko = (size_t)kt * 32;
    unsigned short* da = &sA[buf][db];
    unsigned short* dbp = &sB[buf][db];
#pragma unroll
    for (int j = 0; j < 4; ++j) {
      gload16(gA + ko + (size_t)j * gstep, da + j * 2048);
      gload16(gB + ko + (size_t)j * gstep, dbp + j * 2048);
    }
  };

  STAGE(0, 0);
  __syncthreads();
  int cur = 0;

  for (int kt = 0; kt < nk; ++kt) {
    if (kt + 1 < nk) STAGE(cur ^ 1, kt + 1);
    const unsigned short* pa = &sA[cur][0];
    const unsigned short* pb = &sB[cur][0];
    s16x8 afh[4], afl[4], bfh[4], bfl[4];
#pragma unroll
    for (int mi = 0; mi < 4; ++mi) {
      const int rb = (wm + mi * 16 + arow) * 64;
      afh[mi] = *(const s16x8*)&pa[rb + slotH * 8];
      afl[mi] = *(const s16x8*)&pa[rb + slotL * 8];
    }
#pragma unroll
    for (int ni = 0; ni < 4; ++ni) {
      const int rb = (wn + ni * 16 + arow) * 64;
      bfh[ni] = *(const s16x8*)&pb[rb + slotH * 8];
      bfl[ni] = *(const s16x8*)&pb[rb + slotL * 8];
    }
#pragma unroll
    for (int mi = 0; mi < 4; ++mi)
#pragma unroll
      for (int ni = 0; ni < 4; ++ni) {
        acc[mi][ni] = __builtin_amdgcn_mfma_f32_16x16x32_bf16(afh[mi], bfh[ni], acc[mi][ni], 0, 0, 0);
        acc[mi][ni] = __builtin_amdgcn_mfma_f32_16x16x32_bf16(afh[mi], bfl[ni], acc[mi][ni], 0, 0, 0);
        acc[mi][ni] = __builtin_amdgcn_mfma_f32_16x16x32_bf16(afl[mi], bfh[ni], acc[mi][ni], 0, 0, 0);
      }
    __syncthreads();
    cur ^= 1;
  }

  const int colb = n0 + wn + (l & 15);
  const int rowb = m0 + wm + (l >> 4) * 4;
  const float sdt = (EPI >= 3) ? (tspan[1] - tspan[0]) * (1.0f / 7.0f) : 0.f;

  if (EPI == 1) {
#pragma unroll
    for (int mi = 0; mi < 4; ++mi)
#pragma unroll
      for (int ni = 0; ni < 4; ++ni) {
        const int col = colb + ni * 16;
        const float bc = bias[col];
#pragma unroll
        for (int j = 0; j < 4; ++j) {
          const size_t idx = (size_t)(rowb + mi * 16 + j) * N + col;
          const float v = fast_tanh(acc[mi][ni][j] + bc);
          unsigned short hh, ll; split2(v, hh, ll);
          Oh[idx] = hh; Ol[idx] = ll;
        }
      }
  } else if (EPI == 3) {
    const float c1 = a1 * sdt, c2 = a2 * sdt;
#pragma unroll
    for (int mi = 0; mi < 4; ++mi)
#pragma unroll
      for (int ni = 0; ni < 4; ++ni) {
        const int col = colb + ni * 16;
#pragma unroll
        for (int j = 0; j < 4; ++j) {
          const size_t idx = (size_t)(rowb + mi * 16 + j) * N + col;
          const float f = acc[mi][ni][j];
          const float x = Xin[idx];
          const float a = (accAdd ? ACCb[idx] : x) + c1 * f;
          ACCb[idx] = a;
          const float xt = x + c2 * f;
          unsigned short hh, ll; split2(xt, hh, ll);
          Oh[idx] = hh; Ol[idx] = ll;
        }
      }
  } else {  // EPI == 4
    const float coef = a1 + a2 * sdt;
#pragma unroll
    for (int mi = 0; mi < 4; ++mi)
#pragma unroll
      for (int ni = 0; ni < 4; ++ni) {
        const int col = colb + ni * 16;
#pragma unroll
        for (int j = 0; j < 4; ++j) {
          const size_t idx = (size_t)(rowb + mi * 16 + j) * N + col;
          const float v = Xin[idx] + coef * acc[mi][ni][j];
          Xout[idx] = v;
          unsigned short hh, ll; split2(v, hh, ll);
          Oh[idx] = hh; Ol[idx] = ll;
        }
      }
  }
}

// ---------------------------------------------------------------------------
// 64x64 GEMM for the sequential phase: same staging/swizzle derivation
// (formulas identical: row&7 == l&7 for 16-multiple row bases), 2 gload
// calls per operand per K-step, acc 2x2, 32KB LDS.
// EPI=1: tanh(acc+bias)->Oh/Ol.  EPI=2: Part + blockIdx.z*M*N partial.
// ---------------------------------------------------------------------------
template<int EPI>
__global__ __launch_bounds__(256, 2) void gemm64_k(
    const unsigned short* __restrict__ Ah, const unsigned short* __restrict__ Al,
    const unsigned short* __restrict__ Bh, const unsigned short* __restrict__ Bl,
    const float* __restrict__ bias,
    float* __restrict__ Part,
    unsigned short* __restrict__ Oh, unsigned short* __restrict__ Ol,
    int M, int N, int K, int KS)
{
  __shared__ unsigned short sA[2][64 * 64];
  __shared__ unsigned short sB[2][64 * 64];
  const int tid = threadIdx.x;
  const int w = tid >> 6, l = tid & 63;
  const int m0 = blockIdx.y * 64, n0 = blockIdx.x * 64;
  const size_t kbeg = (size_t)blockIdx.z * (size_t)KS;
  const int wm = (w >> 1) * 32, wn = (w & 1) * 32;

  f32x4 acc[2][2];
#pragma unroll
  for (int a = 0; a < 2; ++a)
#pragma unroll
    for (int b = 0; b < 2; ++b) acc[a][b] = (f32x4){0.f, 0.f, 0.f, 0.f};

  // staging: call j covers rows j*32 + w*8 + (l>>3), phys slot l&7,
  // phys slot holds src slot ssrc = (l&7) ^ (row&7), row&7 = l>>3
  const int rsub = w * 8 + (l >> 3);
  const int ssrc = (l & 7) ^ (l >> 3);
  const int shalf = ssrc >> 2;
  const int schunk = ssrc & 3;
  const unsigned short* gA = (shalf ? Al : Ah) + (size_t)(m0 + rsub) * K + kbeg + schunk * 8;
  const unsigned short* gB = (shalf ? Bl : Bh) + (size_t)(n0 + rsub) * K + kbeg + schunk * 8;
  const size_t gstep = (size_t)32 * (size_t)K;
  const int db = w * 512;

  const int arow = (l & 15);
  const int slotH = ((l >> 4)) ^ (l & 7);
  const int slotL = (4 + (l >> 4)) ^ (l & 7);

  const int nk = KS >> 5;

  auto STAGE = [&](int buf, int kt) {
    const size_t ko = (size_t)kt * 32;
    unsigned short* da = &sA[buf][db];
    unsigned short* dbp = &sB[buf][db];
#pragma unroll
    for (int j = 0; j < 2; ++j) {
      gload16(gA + ko + (size_t)j * gstep, da + j * 2048);
      gload16(gB + ko + (size_t)j * gstep, dbp + j * 2048);
    }
  };

  STAGE(0, 0);
  __syncthreads();
  int cur = 0;

  for (int kt = 0; kt < nk; ++kt) {
    if (kt + 1 < nk) STAGE(cur ^ 1, kt + 1);
    const unsigned short* pa = &sA[cur][0];
    const unsigned short* pb = &sB[cur][0];
    s16x8 afh[2], afl[2], bfh[2], bfl[2];
#pragma unroll
    for (int mi = 0; mi < 2; ++mi) {
      const int rb = (wm + mi * 16 + arow) * 64;
      afh[mi] = *(const s16x8*)&pa[rb + slotH * 8];
      afl[mi] = *(const s16x8*)&pa[rb + slotL * 8];
    }
#pragma unroll
    for (int ni = 0; ni < 2; ++ni) {
      const int rb = (wn + ni * 16 + arow) * 64;
      bfh[ni] = *(const s16x8*)&pb[rb + slotH * 8];
      bfl[ni] = *(const s16x8*)&pb[rb + slotL * 8];
    }
#pragma unroll
    for (int mi = 0; mi < 2; ++mi)
#pragma unroll
      for (int ni = 0; ni < 2; ++ni) {
        acc[mi][ni] = __builtin_amdgcn_mfma_f32_16x16x32_bf16(afh[mi], bfh[ni], acc[mi][ni], 0, 0, 0);
        acc[mi][ni] = __builtin_amdgcn_mfma_f32_16x16x32_bf16(afh[mi], bfl[ni], acc[mi][ni], 0, 0, 0);
        acc[mi][ni] = __builtin_amdgcn_mfma_f32_16x16x32_bf16(afl[mi], bfh[ni], acc[mi][ni], 0, 0, 0);
      }
    __syncthreads();
    cur ^= 1;
  }

  const int colb = n0 + wn + (l & 15);
  const int rowb = m0 + wm + (l >> 4) * 4;

  if (EPI == 1) {
#pragma unroll
    for (int mi = 0; mi < 2; ++mi)
#pragma unroll
      for (int ni = 0; ni < 2; ++ni) {
        const int col = colb + ni * 16;
        const float bc = bias[col];
#pragma unroll
        for (int j = 0; j < 4; ++j) {
          const size_t idx = (size_t)(rowb + mi * 16 + j) * N + col;
          const float v = fast_tanh(acc[mi][ni][j] + bc);
          unsigned short hh, ll; split2(v, hh, ll);
          Oh[idx] = hh; Ol[idx] = ll;
        }
      }
  } else {
    float* dst = Part + (size_t)blockIdx.z * (size_t)M * N;
#pragma unroll
    for (int mi = 0; mi < 2; ++mi)
#pragma unroll
      for (int ni = 0; ni < 2; ++ni) {
        const int col = colb + ni * 16;
#pragma unroll
        for (int j = 0; j < 4; ++j)
          dst[(size_t)(rowb + mi * 16 + j) * N + col] = acc[mi][ni][j];
      }
  }
}

// ---------------------------------------------------------------------------
// seq GEMM2 finish: F = sum_z Part[z]; E = X + sdt*F; [Eout=E];
// v = E [+ Dv]; X = v (+ hi/lo split); [Bout=v]
// ---------------------------------------------------------------------------
__global__ void reduce_axpy_k(const float* __restrict__ part, int S, int MN4,
    const float* __restrict__ tspan,
    float* __restrict__ Xf, unsigned short* __restrict__ Xh, unsigned short* __restrict__ Xl,
    const float* __restrict__ Dv, float* __restrict__ Bout, float* __restrict__ Eout)
{
  const int i = blockIdx.x * blockDim.x + threadIdx.x;
  if (i >= MN4) return;
  const float sdt = (tspan[1] - tspan[0]) * (1.0f / 7.0f);
  const size_t MN = (size_t)MN4 * 4;
  const size_t o = 4 * (size_t)i;
  f32x4 s = *(const f32x4*)(part + o);
  for (int z = 1; z < S; ++z) s += *(const f32x4*)(part + (size_t)z * MN + o);
  f32x4 e = *(const f32x4*)(Xf + o) + sdt * s;
  if (Eout) *(f32x4*)(Eout + o) = e;
  f32x4 v = e;
  if (Dv) v += *(const f32x4*)(Dv + o);
  *(f32x4*)(Xf + o) = v;
  u16x4 hh, ll;
#pragma unroll
  for (int j = 0; j < 4; ++j) { unsigned short h_, l_; split2(v[j], h_, l_); hh[j] = h_; ll[j] = l_; }
  *(u16x4*)(Xh + o) = hh;
  *(u16x4*)(Xl + o) = ll;
  if (Bout) *(f32x4*)(Bout + o) = v;
}

// ---------------------------------------------------------------------------
__global__ void axpy_split_k(
    float* __restrict__ dstF, unsigned short* __restrict__ dstH,
    unsigned short* __restrict__ dstL,
    const float* __restrict__ A, const float* __restrict__ Fv,
    float coef, int n4)
{
  for (int i = blockIdx.x * blockDim.x + threadIdx.x; i < n4;
       i += gridDim.x * blockDim.x) {
    const size_t o = 4 * (size_t)i;
    const f32x4 a = *(const f32x4*)(A + o);
    const f32x4 f = *(const f32x4*)(Fv + o);
    f32x4 v = a + coef * f;
    *(f32x4*)(dstF + o) = v;
    if (dstH) {
      u16x4 hh, ll;
#pragma unroll
      for (int j = 0; j < 4; ++j) { unsigned short h_, l_; split2(v[j], h_, l_); hh[j] = h_; ll[j] = l_; }
      *(u16x4*)(dstH + o) = hh;
      *(u16x4*)(dstL + o) = ll;
    }
  }
}

// ---------------------------------------------------------------------------
__global__ void transpose_split_k(const float* __restrict__ W,
                                  unsigned short* __restrict__ Th,
                                  unsigned short* __restrict__ Tl,
                                  int K, int N)
{
  __shared__ float t[32][33];
  const int tx = threadIdx.x & 31, ty = threadIdx.x >> 5;
  const int n0 = blockIdx.x * 32, k0 = blockIdx.y * 32;
#pragma unroll
  for (int r = 0; r < 4; ++r) {
    const int row = ty + r * 8;
    t[row][tx] = W[(size_t)(k0 + row) * N + n0 + tx];
  }
  __syncthreads();
#pragma unroll
  for (int r = 0; r < 4; ++r) {
    const int row = ty + r * 8;
    const float v = t[tx][row];
    unsigned short hh, ll; split2(v, hh, ll);
    const size_t idx = (size_t)(n0 + row) * K + k0 + tx;
    Th[idx] = hh; Tl[idx] = ll;
  }
}

// ---------------------------------------------------------------------------
extern "C" void kernel_launch(void* const* d_in, const int* in_sizes, int n_in,
                              void* d_out, int out_size, void* d_ws, size_t ws_size,
                              hipStream_t stream)
{
  const float* Bin   = (const float*)d_in[0];
  const float* tspan = (const float*)d_in[1];
  const float* W1    = (const float*)d_in[2];
  const float* b1    = (const float*)d_in[3];
  const float* W2    = (const float*)d_in[4];

  const int n = in_sizes[1];                 // 16
  const int h = in_sizes[3];                 // 4096
  const int d = in_sizes[2] / h;             // 1024
  const int batch = in_sizes[0] / (n * d);   // 256
  const int S = 7;                           // fine_steps-1
  const int MAXIT = 2;
  const size_t NB = (size_t)batch * d;

  float* Bw = (float*)d_out;

  uint8_t* wsb = (uint8_t*)d_ws;
  size_t off = 0;
  auto carve = [&](size_t bytes) -> void* {
    off = (off + 255) & ~(size_t)255;
    void* p = wsb + off; off += bytes; return p;
  };

  const size_t WH = (size_t)d * h;
  unsigned short* W1Th = (unsigned short*)carve(WH * 2);
  unsigned short* W1Tl = (unsigned short*)carve(WH * 2);
  unsigned short* W2Th = (unsigned short*)carve(WH * 2);
  unsigned short* W2Tl = (unsigned short*)carve(WH * 2);
  float* Dbuf = (float*)carve((size_t)(n - 1) * NB * 4);
  float* Eb   = (float*)carve((size_t)n * NB * 4);

  // seq GEMM2 partials: z=4 x batch x d (4.2 MB)
  const int SPL2 = 4;
  float* Part = (float*)carve((size_t)SPL2 * NB * 4);

  // per node: Cst4 + Csh2 + Csl2 + Xf4 + Xh2 + Xl2 + ACC4 (XT aliases Cs) + Y4
  const size_t per_node = NB * 20 + (size_t)batch * h * 4;
  int c;
  {
    size_t remb = ws_size > off + (1u << 20) ? ws_size - off - (1u << 20) : 0;
    c = (int)(remb / per_node);
    if (c < 1) c = 1;
    if (c > n - 1) c = n - 1;
  }
  const size_t CE = (size_t)c * NB;
  float*          Cst = (float*)carve(CE * 4);
  unsigned short* Csh = (unsigned short*)carve(CE * 2);
  unsigned short* Csl = (unsigned short*)carve(CE * 2);
  float*          Xf  = (float*)carve(CE * 4);
  unsigned short* Xh  = (unsigned short*)carve(CE * 2);
  unsigned short* Xl  = (unsigned short*)carve(CE * 2);
  float*          ACC = (float*)carve(CE * 4);
  unsigned short* Yh  = (unsigned short*)carve((size_t)c * batch * h * 2);
  unsigned short* Yl  = (unsigned short*)carve((size_t)c * batch * h * 2);
  unsigned short* XTh = Csh;   // time-disjoint with coarse sweep
  unsigned short* XTl = Csl;

  auto ewg = [](size_t n4) -> int {
    size_t g = (n4 + 255) / 256;
    if (g > 2048) g = 2048; if (g < 1) g = 1;
    return (int)g;
  };
  auto axpy = [&](float* dF, unsigned short* dH, unsigned short* dL,
                  const float* A, const float* Fv, float coef, size_t ne) {
    const int n4 = (int)(ne / 4);
    axpy_split_k<<<ewg(n4), 256, 0, stream>>>(dF, dH, dL, A, Fv, coef, n4);
  };
  // vect g1: 128^2, fused tanh+split epilogue
  auto g1 = [&](const unsigned short* xh, const unsigned short* xl, int M) {
    gemm_k<1><<<dim3(h / 128, M / 128, 1), 256, 0, stream>>>(
        xh, xl, W1Th, W1Tl, b1, Yh, Yl,
        nullptr, nullptr, nullptr, tspan, 0.f, 0.f, 0, M, h, d, d);
  };
  auto g2rk = [&](int M, float a1, float a2, int add) {
    gemm_k<3><<<dim3(d / 128, M / 128, 1), 256, 0, stream>>>(
        Yh, Yl, W2Th, W2Tl, nullptr, XTh, XTl,
        Xf, ACC, nullptr, tspan, a1, a2, add, M, d, h, h);
  };
  auto g2ax = [&](int M, float* dF, unsigned short* dH, unsigned short* dL,
                  const float* Xin, float a1, float a2) {
    gemm_k<4><<<dim3(d / 128, M / 128, 1), 256, 0, stream>>>(
        Yh, Yl, W2Th, W2Tl, nullptr, dH, dL,
        Xin, nullptr, dF, tspan, a1, a2, 0, M, d, h, h);
  };

  // ---- prep ---------------------------------------------------------------
  hipMemcpyAsync(Bw, Bin, (size_t)n * NB * 4, hipMemcpyDeviceToDevice, stream);
  transpose_split_k<<<dim3(h / 32, d / 32), 256, 0, stream>>>(W1, W1Th, W1Tl, d, h);
  transpose_split_k<<<dim3(d / 32, h / 32), 256, 0, stream>>>(W2, W2Th, W2Tl, h, d);

  const int MN4d = (int)(NB / 4);

  // ---- Parareal outer loop ------------------------------------------------
  for (int i = 1; i <= MAXIT + 1; ++i) {
    const int rem = n - i;

    for (int base = 0; base < rem; base += c) {
      const int cc = (rem - base) < c ? (rem - base) : c;
      const int M = cc * batch;
      const size_t ne = (size_t)M * d;
      const int j0 = i - 1 + base;
      const float* src = Bw + (size_t)j0 * NB;

      if (i == 1) {
        // coarse Euler sweep (i>=2 reuses Eb from previous sequential phase)
        axpy(Cst, Csh, Csl, src, src, 0.f, ne);
        for (int s = 0; s < S; ++s) {
          g1(Csh, Csl, M);
          g2ax(M, Cst, Csh, Csl, Cst, 0.f, 1.f);
        }
      }
      // fine RK4 sweep
      axpy(Xf, Xh, Xl, src, src, 0.f, ne);
      for (int s = 0; s < S; ++s) {
        g1(Xh, Xl, M);   g2rk(M, 1.f / 6.f, 0.5f, 0);   // k1
        g1(XTh, XTl, M); g2rk(M, 1.f / 3.f, 0.5f, 1);   // k2
        g1(XTh, XTl, M); g2rk(M, 1.f / 3.f, 1.0f, 1);   // k3
        g1(XTh, XTl, M); g2ax(M, Xf, Xh, Xl, ACC, 0.f, 1.f / 6.f);  // k4
      }
      const float* Cref = (i == 1) ? Cst : (Eb + (size_t)j0 * NB);
      axpy(Dbuf + (size_t)base * NB, nullptr, nullptr, Xf, Cref, -1.f, ne);
    }

    // ---- sequential Parareal correction: 3 dispatches/substep, 64^2 -------
    const float* start = Bw + (size_t)(i - 1) * NB;
    axpy(Xf, Xh, Xl, start, start, 0.f, NB);
    for (int m = 0; m < rem; ++m) {
      for (int s = 0; s < S; ++s) {
        // GEMM1: 64x4 = 256 WGs, z=1, fused tanh+split -> Yh/Yl
        gemm64_k<1><<<dim3(h / 64, batch / 64, 1), 256, 0, stream>>>(
            Xh, Xl, W1Th, W1Tl, b1, nullptr, Yh, Yl, batch, h, d, d);
        // GEMM2: 16x4x4 = 256 WGs, z=4 partials
        gemm64_k<2><<<dim3(d / 64, batch / 64, SPL2), 256, 0, stream>>>(
            Yh, Yl, W2Th, W2Tl, nullptr, Part, nullptr, nullptr,
            batch, d, h, h / SPL2);
        const bool last = (s == S - 1);
        reduce_axpy_k<<<(MN4d + 255) / 256, 256, 0, stream>>>(
            Part, SPL2, MN4d, tspan, Xf, Xh, Xl,
            last ? Dbuf + (size_t)m * NB : nullptr,
            last ? Bw + (size_t)(i + m) * NB : nullptr,
            last ? Eb + (size_t)(i - 1 + m) * NB : nullptr);
      }
    }
  }
}